// Round 2
// 634.553 us; speedup vs baseline: 1.0517x; 1.0517x over previous
//
#include <hip/hip_runtime.h>
#include <stdint.h>

static constexpr int Bn = 16, Tn = 2048, En = 1024, NHn = 16, HDn = 64, NLEVn = 12;

typedef __attribute__((ext_vector_type(8))) short short8;
typedef __attribute__((ext_vector_type(4))) float floatx4;

__device__ __forceinline__ unsigned short f2bf(float f) {
  unsigned int u = __float_as_uint(f);
  u += 0x7fffu + ((u >> 16) & 1u);
  return (unsigned short)(u >> 16);
}
__device__ __forceinline__ float bf2f(unsigned short s) {
  return __uint_as_float(((unsigned int)s) << 16);
}

__device__ __forceinline__ void async16(const unsigned short* g, unsigned short* l) {
  __builtin_amdgcn_global_load_lds(
      (const __attribute__((address_space(1))) unsigned int*)g,
      (__attribute__((address_space(3))) unsigned int*)l, 16, 0, 0);
}

// ---------------- fp32 -> bf16 convert ----------------
__global__ void k_cvt(const float* __restrict__ in, unsigned short* __restrict__ out, int n4) {
  int i = blockIdx.x * 256 + threadIdx.x;
  if (i < n4) {
    float4 v = ((const float4*)in)[i];
    ushort4 o;
    o.x = f2bf(v.x); o.y = f2bf(v.y); o.z = f2bf(v.z); o.w = f2bf(v.w);
    ((ushort4*)out)[i] = o;
  }
}

// ---------------- per-head prefix scan of log(sigmoid(A)) ----------------
__global__ void k_scan(const float* __restrict__ A_log, const float* __restrict__ A_bias,
                       float* __restrict__ cs) {
  int h = blockIdx.x;
  int tid = threadIdx.x;
  __shared__ float part[256];
  float loc[8];
  float run = 0.f;
#pragma unroll
  for (int j = 0; j < 8; j++) {
    int t = tid * 8 + j;
    float x = A_log[t * NHn + h] + A_bias[t * NHn + h];
    float ls = -log1pf(__expf(-x));
    run += ls;
    loc[j] = run;
  }
  part[tid] = run;
  __syncthreads();
  for (int d = 1; d < 256; d <<= 1) {
    float v = (tid >= d) ? part[tid - d] : 0.f;
    __syncthreads();
    part[tid] += v;
    __syncthreads();
  }
  float off = (tid > 0) ? part[tid - 1] : 0.f;
#pragma unroll
  for (int j = 0; j < 8; j++) cs[(tid * 8 + j) * NHn + h] = loc[j] + off;
}

// ---------------- unnormalized weights P[h][t][s] (bf16) + row sums ----------------
__global__ void k_weights(const float* __restrict__ L, const float* __restrict__ Lb,
                          const int* __restrict__ levels, const float* __restrict__ cs,
                          unsigned short* __restrict__ P, float* __restrict__ denom) {
  int t = blockIdx.x;
  int tid = threadIdx.x;
  __shared__ float Lrow[NHn * NLEVn];
  __shared__ float cst[NHn];
  __shared__ float dsum[NHn];
  if (tid < NHn * NLEVn) Lrow[tid] = L[t * NHn * NLEVn + tid] + Lb[t * NHn * NLEVn + tid];
  if (tid < NHn) { cst[tid] = cs[t * NHn + tid]; dsum[tid] = 0.f; }
  __syncthreads();
  float acc[NHn];
#pragma unroll
  for (int h = 0; h < NHn; h++) acc[h] = 0.f;
  for (int s = tid; s < Tn; s += 256) {
    int lev = levels[(size_t)t * Tn + s];
    bool causal = (s <= t);
    float csr[NHn];
    const float4* c4 = (const float4*)(cs + s * NHn);
#pragma unroll
    for (int q = 0; q < 4; q++) {
      float4 v = c4[q];
      csr[q * 4 + 0] = v.x; csr[q * 4 + 1] = v.y; csr[q * 4 + 2] = v.z; csr[q * 4 + 3] = v.w;
    }
#pragma unroll
    for (int h = 0; h < NHn; h++) {
      float w = 1.f;   // exp(0) for s > t (mask writes 0, not -inf)
      if (causal) {
        float dec = __expf(cst[h] - csr[h]);
        w = __expf(Lrow[h * NLEVn + lev] * dec);
      }
      unsigned short pb = f2bf(w);
      acc[h] += bf2f(pb);
      P[((size_t)h * Tn + t) * Tn + s] = pb;
    }
  }
  int lane = tid & 63;
#pragma unroll
  for (int h = 0; h < NHn; h++) {
    float v = acc[h];
    for (int o = 32; o > 0; o >>= 1) v += __shfl_down(v, o, 64);
    if (lane == 0) atomicAdd(&dsum[h], v);
  }
  __syncthreads();
  if (tid < NHn) denom[(size_t)tid * Tn + t] = dsum[tid];
}

// ================= GEMM 1: v = x@Wv^T + bv, 256x128 block, fused transpose =================
__global__ __launch_bounds__(512)
void k_gemm_v(const unsigned short* __restrict__ A, const unsigned short* __restrict__ Bm,
              const float* __restrict__ bias, unsigned short* __restrict__ vt) {
  __shared__ unsigned short smem[24576];     // 48 KB: As(32K) | Bs(16K); epilogue reuses as Ct
  unsigned short* As = smem;                 // 256 x 64
  unsigned short* Bs = smem + 16384;         // 128 x 64
  const int K = 1024;
  int tid = threadIdx.x;
  int wave = tid >> 6, lane = tid & 63;
  int wm = wave >> 1, wn = wave & 1;         // 4 x 2 waves of 64x64 tiles

  int flat = blockIdx.y * 8 + blockIdx.x;    // gridDim.x == 8
  int xcd = flat & 7, slot = flat >> 3;      // slot 0..127
  int strip = xcd * 16 + (slot >> 3);        // 128 strips, 16 per XCD
  int nt = slot & 7;
  int bm = strip * 256, bn = nt * 128;

  floatx4 zero4 = {0.f, 0.f, 0.f, 0.f};
  floatx4 acc[4][4];
#pragma unroll
  for (int i = 0; i < 4; i++)
#pragma unroll
    for (int j = 0; j < 4; j++) acc[i][j] = zero4;

  for (int k0 = 0; k0 < K; k0 += 64) {
    __syncthreads();
#pragma unroll
    for (int j = 0; j < 4; j++) {            // A: 256 rows x 64 k (32KB)
      int f = j * 512 + tid;
      int r = f >> 3, c = f & 7;
      int cg = c ^ (r & 7);
      async16(&A[(size_t)(bm + r) * K + k0 + cg * 8], &As[f * 8]);
    }
#pragma unroll
    for (int j = 0; j < 2; j++) {            // B: 128 rows x 64 k (16KB)
      int f = j * 512 + tid;
      int r = f >> 3, c = f & 7;
      int cg = c ^ (r & 7);
      async16(&Bm[(size_t)(bn + r) * K + k0 + cg * 8], &Bs[f * 8]);
    }
    __syncthreads();
#pragma unroll
    for (int kk = 0; kk < 2; kk++) {
      short8 af[4], bfr[4];
      int cgk = kk * 4 + (lane >> 4);
#pragma unroll
      for (int i = 0; i < 4; i++) {
        int m = wm * 64 + i * 16 + (lane & 15);
        af[i] = *(const short8*)&As[m * 64 + ((cgk ^ (m & 7)) * 8)];
        int n = wn * 64 + i * 16 + (lane & 15);
        bfr[i] = *(const short8*)&Bs[n * 64 + ((cgk ^ (n & 7)) * 8)];
      }
#pragma unroll
      for (int i = 0; i < 4; i++)
#pragma unroll
        for (int j = 0; j < 4; j++)
          acc[i][j] = __builtin_amdgcn_mfma_f32_16x16x32_bf16(af[i], bfr[j], acc[i][j], 0, 0, 0);
    }
  }

  // ---- fused transpose epilogue: write vt[h][b][d][t] ----
  int b = bm >> 11, t0 = bm & 2047;
  unsigned short* Ct = smem;                 // 64 cols x (256+8) rows
  const int S = 264;
#pragma unroll 1
  for (int pass = 0; pass < 2; pass++) {
    __syncthreads();
    if (wn == pass) {
#pragma unroll
      for (int i = 0; i < 4; i++) {
#pragma unroll
        for (int j = 0; j < 4; j++) {
          int colL = j * 16 + (lane & 15);
          float bia = bias[bn + pass * 64 + colL];
          int rowb = wm * 64 + i * 16 + (lane >> 4) * 4;
          ushort4 p;
          p.x = f2bf(acc[i][j][0] + bia);
          p.y = f2bf(acc[i][j][1] + bia);
          p.z = f2bf(acc[i][j][2] + bia);
          p.w = f2bf(acc[i][j][3] + bia);
          *(ushort4*)&Ct[colL * S + rowb] = p;
        }
      }
    }
    __syncthreads();
#pragma unroll
    for (int cc = 0; cc < 4; cc++) {
      int colL = wave * 8 + cc * 2 + (lane >> 5);
      int gc = bn + pass * 64 + colL;
      int h = gc >> 6, d = gc & 63;
      int tt = (lane & 31) * 8;
      short8 v = *(const short8*)&Ct[colL * S + tt];
      *(short8*)&vt[((size_t)((h * Bn + b) * HDn + d)) * Tn + t0 + tt] = v;
    }
  }
}

// ================= GEMM 2: attn @ v (per head) =================
// 256x256 tile, 512 threads (8 waves 2x4), BK=64, double-buffered 128 KiB LDS,
// 4-phase/K-tile schedule with counted vmcnt(6) (never 0 in loop).
// Each phase computes one GLOBAL 128x128 quadrant (Mh,Nh) of the output tile;
// every wave works strictly inside that quadrant (rows Mh*128 + wm*64 + ...,
// cols Nh*128 + wn*32 + ...), so a phase touches ONLY the half-tiles that its
// vmcnt(6) has drained. Stage order per K-tile: Ah0, Bh0, Bh1, Ah1; quadrant
// order: (0,0), (0,1), (1,1), (1,0).

#define STAGE_A(kt, half, buf)                                                   \
  {                                                                              \
    _Pragma("unroll")                                                            \
    for (int j_ = 0; j_ < 2; j_++) {                                             \
      int f_ = j_ * 512 + tid;                                                   \
      int r_ = f_ >> 3, c_ = f_ & 7;                                             \
      int cg_ = c_ ^ (r_ & 7);                                                   \
      async16(&Ap[(size_t)(bm + (half) * 128 + r_) * K + (kt) * 64 + cg_ * 8],   \
              &smem[(buf) * 32768 + ((half) * 128 + r_) * 64 + c_ * 8]);         \
    }                                                                            \
  }

#define STAGE_B(kt, half, buf)                                                   \
  {                                                                              \
    _Pragma("unroll")                                                            \
    for (int j_ = 0; j_ < 2; j_++) {                                             \
      int f_ = j_ * 512 + tid;                                                   \
      int r_ = f_ >> 3, c_ = f_ & 7;                                             \
      int cg_ = c_ ^ (r_ & 7);                                                   \
      async16(&Bp[(size_t)(bn + (half) * 128 + r_) * K + (kt) * 64 + cg_ * 8],   \
              &smem[(buf) * 32768 + 16384 + ((half) * 128 + r_) * 64 + c_ * 8]); \
    }                                                                            \
  }

#define LOAD_A(buf, Mh)                                                          \
  {                                                                              \
    _Pragma("unroll")                                                            \
    for (int ii_ = 0; ii_ < 4; ii_++) {                                          \
      int m_ = (Mh) * 128 + wm * 64 + ii_ * 16 + (lane & 15);                    \
      _Pragma("unroll")                                                          \
      for (int kk_ = 0; kk_ < 2; kk_++) {                                        \
        int cgk_ = kk_ * 4 + (lane >> 4);                                        \
        aR[ii_][kk_] =                                                           \
            *(const short8*)&smem[(buf) * 32768 + m_ * 64 + ((cgk_ ^ (m_ & 7)) * 8)]; \
      }                                                                          \
    }                                                                            \
  }

#define LOAD_B(buf, Nh)                                                          \
  {                                                                              \
    _Pragma("unroll")                                                            \
    for (int jj_ = 0; jj_ < 2; jj_++) {                                          \
      int n_ = (Nh) * 128 + wn * 32 + jj_ * 16 + (lane & 15);                    \
      _Pragma("unroll")                                                          \
      for (int kk_ = 0; kk_ < 2; kk_++) {                                        \
        int cgk_ = kk_ * 4 + (lane >> 4);                                        \
        bR[jj_][kk_] = *(const short8*)&smem[(buf) * 32768 + 16384 + n_ * 64 +   \
                                             ((cgk_ ^ (n_ & 7)) * 8)];           \
      }                                                                          \
    }                                                                            \
  }

#define MFMA16(Mh, Nh)                                                           \
  {                                                                              \
    __builtin_amdgcn_s_setprio(1);                                               \
    _Pragma("unroll")                                                            \
    for (int kk_ = 0; kk_ < 2; kk_++)                                            \
      _Pragma("unroll")                                                          \
      for (int ii_ = 0; ii_ < 4; ii_++)                                          \
        _Pragma("unroll")                                                        \
        for (int jj_ = 0; jj_ < 2; jj_++)                                        \
          acc[(Mh) * 4 + ii_][(Nh) * 2 + jj_] = __builtin_amdgcn_mfma_f32_16x16x32_bf16( \
              aR[ii_][kk_], bR[jj_][kk_], acc[(Mh) * 4 + ii_][(Nh) * 2 + jj_], 0, 0, 0); \
    __builtin_amdgcn_s_setprio(0);                                               \
  }

#define WAIT6 asm volatile("s_waitcnt vmcnt(6)" ::: "memory")
#define BAR                                                                      \
  {                                                                              \
    asm volatile("" ::: "memory");                                               \
    __builtin_amdgcn_s_barrier();                                                \
    asm volatile("" ::: "memory");                                               \
  }

__global__ __launch_bounds__(512, 2)
void k_gemm_attn(const unsigned short* __restrict__ P, const unsigned short* __restrict__ vt,
                 const float* __restrict__ denom, unsigned short* __restrict__ outp) {
  __shared__ unsigned short smem[65536];     // 128 KiB: 2 x (A 256x64 | B 256x64)
  const int K = Tn;
  int tid = threadIdx.x;
  int wave = tid >> 6, lane = tid & 63;
  int wm = wave >> 2, wn = wave & 3;         // per-quadrant: 2x4 waves of 64x32

  int flat = blockIdx.y * 8 + blockIdx.x;    // gridDim = (8, 64)
  int wg = (flat & 7) * 64 + (flat >> 3);    // 64 consecutive tiles per XCD (2 heads)
  int h = wg >> 5;                           // 32 tiles per head (8 M x 4 N)
  int mt = (wg >> 2) & 7, nt = wg & 3;
  int bm = mt * 256, bn = nt * 256;

  const unsigned short* Ap = P + (size_t)h * Tn * Tn;
  const unsigned short* Bp = vt + (size_t)h * (Bn * HDn) * Tn;

  floatx4 zero4 = {0.f, 0.f, 0.f, 0.f};
  floatx4 acc[8][4];
#pragma unroll
  for (int i = 0; i < 8; i++)
#pragma unroll
    for (int j = 0; j < 4; j++) acc[i][j] = zero4;

  short8 aR[4][2], bR[2][2];

  // prologue: stage K-tile 0 into buf0 (order must match steady-state)
  STAGE_A(0, 0, 0);
  STAGE_B(0, 0, 0);
  STAGE_B(0, 1, 0);
  STAGE_A(0, 1, 0);

  const int nk = K / 64;                     // 32
  for (int t = 0; t < nk; t++) {
    int buf = t & 1, nbuf = buf ^ 1;
    int tn = (t < nk - 1) ? t + 1 : nk - 1;  // clamp: last iter restages (harmless)

    // phase 1: quadrant (0,0) — needs Ah0[t], Bh0[t]
    STAGE_A(tn, 0, nbuf);
    WAIT6; BAR;
    LOAD_A(buf, 0);
    LOAD_B(buf, 0);
    MFMA16(0, 0);
    BAR;
    // phase 2: quadrant (0,1) — needs Bh1[t], reuses aR (Mh=0)
    STAGE_B(tn, 0, nbuf);
    WAIT6; BAR;
    LOAD_B(buf, 1);
    MFMA16(0, 1);
    BAR;
    // phase 3: quadrant (1,1) — needs Ah1[t], reuses bR (Nh=1)
    STAGE_B(tn, 1, nbuf);
    WAIT6; BAR;
    LOAD_A(buf, 1);
    MFMA16(1, 1);
    BAR;
    // phase 4: quadrant (1,0) — re-reads Bh0[t], reuses aR (Mh=1)
    STAGE_A(tn, 1, nbuf);
    WAIT6; BAR;
    LOAD_B(buf, 0);
    MFMA16(1, 0);
    BAR;
  }
  asm volatile("s_waitcnt vmcnt(0)" ::: "memory");  // drain before endpgm

  // epilogue: scale by 1/denom, scatter col=(b,d) -> outp[b][row][h*64+d]
#pragma unroll
  for (int i = 0; i < 8; i++) {
    int rb = bm + (i >> 2) * 128 + wm * 64 + (i & 3) * 16 + (lane >> 4) * 4;
#pragma unroll
    for (int r = 0; r < 4; r++) {
      int row = rb + r;
      float sc = 1.f / denom[(size_t)h * Tn + row];
#pragma unroll
      for (int j = 0; j < 4; j++) {
        int col = bn + (j >> 1) * 128 + wn * 32 + (j & 1) * 16 + (lane & 15);
        int b = col >> 6, d = col & 63;
        outp[((size_t)(b * Tn + row)) * En + h * HDn + d] = f2bf(acc[i][j][r] * sc);
      }
    }
  }
}

// ================= GEMM 3: out = o@Wo^T + bo, 128x128 block =================
__global__ __launch_bounds__(256)
void k_gemm_out(const unsigned short* __restrict__ A, const unsigned short* __restrict__ Bm,
                const float* __restrict__ bias, float* __restrict__ out) {
  __shared__ unsigned short As[128 * 64];
  __shared__ unsigned short Bs[128 * 64];
  const int K = 1024, N = 1024;
  int tid = threadIdx.x;
  int wave = tid >> 6, lane = tid & 63;
  int wm = wave >> 1, wn = wave & 1;

  int flat = blockIdx.y * 8 + blockIdx.x;
  int xcd = flat & 7, slot = flat >> 3;
  int strip = xcd * 32 + (slot >> 3);
  int nt = slot & 7;
  int bm = strip * 128, bn = nt * 128;

  floatx4 zero4 = {0.f, 0.f, 0.f, 0.f};
  floatx4 acc[4][4];
#pragma unroll
  for (int i = 0; i < 4; i++)
#pragma unroll
    for (int j = 0; j < 4; j++) acc[i][j] = zero4;

  for (int k0 = 0; k0 < K; k0 += 64) {
    __syncthreads();
#pragma unroll
    for (int j = 0; j < 4; j++) {
      int f = j * 256 + tid;
      int r = f >> 3, c = f & 7;
      int cg = c ^ (r & 7);
      async16(&A[(size_t)(bm + r) * K + k0 + cg * 8], &As[f * 8]);
    }
#pragma unroll
    for (int j = 0; j < 4; j++) {
      int f = j * 256 + tid;
      int r = f >> 3, c = f & 7;
      int cg = c ^ (r & 7);
      async16(&Bm[(size_t)(bn + r) * K + k0 + cg * 8], &Bs[f * 8]);
    }
    __syncthreads();
#pragma unroll
    for (int kk = 0; kk < 2; kk++) {
      short8 af[4], bfr[4];
      int cgk = kk * 4 + (lane >> 4);
#pragma unroll
      for (int i = 0; i < 4; i++) {
        int m = wm * 64 + i * 16 + (lane & 15);
        af[i] = *(const short8*)&As[m * 64 + ((cgk ^ (m & 7)) * 8)];
        int n = wn * 64 + i * 16 + (lane & 15);
        bfr[i] = *(const short8*)&Bs[n * 64 + ((cgk ^ (n & 7)) * 8)];
      }
#pragma unroll
      for (int i = 0; i < 4; i++)
#pragma unroll
        for (int j = 0; j < 4; j++)
          acc[i][j] = __builtin_amdgcn_mfma_f32_16x16x32_bf16(af[i], bfr[j], acc[i][j], 0, 0, 0);
    }
  }
#pragma unroll
  for (int i = 0; i < 4; i++) {
#pragma unroll
    for (int j = 0; j < 4; j++) {
#pragma unroll
      for (int r = 0; r < 4; r++) {
        int row = bm + wm * 64 + i * 16 + (lane >> 4) * 4 + r;
        int col = bn + wn * 64 + j * 16 + (lane & 15);
        out[(size_t)row * N + col] = acc[i][j][r] + bias[col];
      }
    }
  }
}

extern "C" void kernel_launch(void* const* d_in, const int* in_sizes, int n_in,
                              void* d_out, int out_size, void* d_ws, size_t ws_size,
                              hipStream_t stream) {
  const float* x      = (const float*)d_in[0];
  // d_in[1..4] = Wq, bq, Wk, bk — unused by the reference
  const float* Wv     = (const float*)d_in[5];
  const float* bv     = (const float*)d_in[6];
  const float* A_log  = (const float*)d_in[7];
  const float* A_bias = (const float*)d_in[8];
  const float* L      = (const float*)d_in[9];
  const float* Lb     = (const float*)d_in[10];
  const float* Wo     = (const float*)d_in[11];
  const float* bo     = (const float*)d_in[12];
  const int* levels   = (const int*)d_in[13];
  float* out = (float*)d_out;

  // workspace layout (bytes); Pw aliases xb (dead after k_gemm_v)
  char* ws = (char*)d_ws;
  float* cs            = (float*)(ws + 0);                  // 128 KiB
  float* denom         = (float*)(ws + 131072);             // 128 KiB
  unsigned short* Wvb  = (unsigned short*)(ws + 262144);    // 2 MiB
  unsigned short* Wob  = (unsigned short*)(ws + 2359296);   // 2 MiB
  unsigned short* xb   = (unsigned short*)(ws + 4456448);   // 64 MiB
  unsigned short* Pw   = (unsigned short*)(ws + 4456448);   // 128 MiB (aliases xb)
  unsigned short* vt   = (unsigned short*)(ws + 138674176); // 64 MiB
  unsigned short* outp = (unsigned short*)(ws + 205783040); // 64 MiB
  if (ws_size < 272891904ULL) return;

  int nx4 = Bn * Tn * En / 4;
  k_cvt<<<(nx4 + 255) / 256, 256, 0, stream>>>(x, xb, nx4);
  int nw4 = En * En / 4;
  k_cvt<<<(nw4 + 255) / 256, 256, 0, stream>>>(Wv, Wvb, nw4);
  k_cvt<<<(nw4 + 255) / 256, 256, 0, stream>>>(Wo, Wob, nw4);
  k_scan<<<NHn, 256, 0, stream>>>(A_log, A_bias, cs);

  k_gemm_v<<<dim3(8, 128), 512, 0, stream>>>(xb, Wvb, bv, vt);

  k_weights<<<Tn, 256, 0, stream>>>(L, Lb, levels, cs, Pw, denom);

  k_gemm_attn<<<dim3(8, 64), 512, 0, stream>>>(Pw, vt, denom, outp);

  k_gemm_out<<<dim3(8, 256), 256, 0, stream>>>(outp, Wob, bo, out);
}

// Round 3
// 618.590 us; speedup vs baseline: 1.0789x; 1.0258x over previous
//
#include <hip/hip_runtime.h>
#include <stdint.h>

static constexpr int Bn = 16, Tn = 2048, En = 1024, NHn = 16, HDn = 64, NLEVn = 12;

typedef __attribute__((ext_vector_type(8))) short short8;
typedef __attribute__((ext_vector_type(4))) float floatx4;

__device__ __forceinline__ unsigned short f2bf(float f) {
  unsigned int u = __float_as_uint(f);
  u += 0x7fffu + ((u >> 16) & 1u);
  return (unsigned short)(u >> 16);
}
__device__ __forceinline__ float bf2f(unsigned short s) {
  return __uint_as_float(((unsigned int)s) << 16);
}

__device__ __forceinline__ void async16(const unsigned short* g, unsigned short* l) {
  __builtin_amdgcn_global_load_lds(
      (const __attribute__((address_space(1))) unsigned int*)g,
      (__attribute__((address_space(3))) unsigned int*)l, 16, 0, 0);
}

// ---------------- fp32 -> bf16 convert ----------------
__global__ void k_cvt(const float* __restrict__ in, unsigned short* __restrict__ out, int n4) {
  int i = blockIdx.x * 256 + threadIdx.x;
  if (i < n4) {
    float4 v = ((const float4*)in)[i];
    ushort4 o;
    o.x = f2bf(v.x); o.y = f2bf(v.y); o.z = f2bf(v.z); o.w = f2bf(v.w);
    ((ushort4*)out)[i] = o;
  }
}

// ---------------- per-head prefix scan of log(sigmoid(A)) ----------------
__global__ void k_scan(const float* __restrict__ A_log, const float* __restrict__ A_bias,
                       float* __restrict__ cs) {
  int h = blockIdx.x;
  int tid = threadIdx.x;
  __shared__ float part[256];
  float loc[8];
  float run = 0.f;
#pragma unroll
  for (int j = 0; j < 8; j++) {
    int t = tid * 8 + j;
    float x = A_log[t * NHn + h] + A_bias[t * NHn + h];
    float ls = -log1pf(__expf(-x));
    run += ls;
    loc[j] = run;
  }
  part[tid] = run;
  __syncthreads();
  for (int d = 1; d < 256; d <<= 1) {
    float v = (tid >= d) ? part[tid - d] : 0.f;
    __syncthreads();
    part[tid] += v;
    __syncthreads();
  }
  float off = (tid > 0) ? part[tid - 1] : 0.f;
#pragma unroll
  for (int j = 0; j < 8; j++) cs[(tid * 8 + j) * NHn + h] = loc[j] + off;
}

// ---------------- unnormalized weights P[h][t][s] (bf16) + row sums ----------------
__global__ void k_weights(const float* __restrict__ L, const float* __restrict__ Lb,
                          const int* __restrict__ levels, const float* __restrict__ cs,
                          unsigned short* __restrict__ P, float* __restrict__ denom) {
  int t = blockIdx.x;
  int tid = threadIdx.x;
  __shared__ float Lrow[NHn * NLEVn];
  __shared__ float cst[NHn];
  __shared__ float dsum[NHn];
  if (tid < NHn * NLEVn) Lrow[tid] = L[t * NHn * NLEVn + tid] + Lb[t * NHn * NLEVn + tid];
  if (tid < NHn) { cst[tid] = cs[t * NHn + tid]; dsum[tid] = 0.f; }
  __syncthreads();
  float acc[NHn];
#pragma unroll
  for (int h = 0; h < NHn; h++) acc[h] = 0.f;
  for (int s = tid; s < Tn; s += 256) {
    int lev = levels[(size_t)t * Tn + s];
    bool causal = (s <= t);
    float csr[NHn];
    const float4* c4 = (const float4*)(cs + s * NHn);
#pragma unroll
    for (int q = 0; q < 4; q++) {
      float4 v = c4[q];
      csr[q * 4 + 0] = v.x; csr[q * 4 + 1] = v.y; csr[q * 4 + 2] = v.z; csr[q * 4 + 3] = v.w;
    }
#pragma unroll
    for (int h = 0; h < NHn; h++) {
      float w = 1.f;   // exp(0) for s > t (mask writes 0, not -inf)
      if (causal) {
        float dec = __expf(cst[h] - csr[h]);
        w = __expf(Lrow[h * NLEVn + lev] * dec);
      }
      unsigned short pb = f2bf(w);
      acc[h] += bf2f(pb);
      P[((size_t)h * Tn + t) * Tn + s] = pb;
    }
  }
  int lane = tid & 63;
#pragma unroll
  for (int h = 0; h < NHn; h++) {
    float v = acc[h];
    for (int o = 32; o > 0; o >>= 1) v += __shfl_down(v, o, 64);
    if (lane == 0) atomicAdd(&dsum[h], v);
  }
  __syncthreads();
  if (tid < NHn) denom[(size_t)tid * Tn + t] = dsum[tid];
}

// ================= GEMM 1: v = x@Wv^T + bv, 256x128 block, fused transpose =================
__global__ __launch_bounds__(512)
void k_gemm_v(const unsigned short* __restrict__ A, const unsigned short* __restrict__ Bm,
              const float* __restrict__ bias, unsigned short* __restrict__ vt) {
  __shared__ unsigned short smem[24576];     // 48 KB: As(32K) | Bs(16K); epilogue reuses as Ct
  unsigned short* As = smem;                 // 256 x 64
  unsigned short* Bs = smem + 16384;         // 128 x 64
  const int K = 1024;
  int tid = threadIdx.x;
  int wave = tid >> 6, lane = tid & 63;
  int wm = wave >> 1, wn = wave & 1;         // 4 x 2 waves of 64x64 tiles

  int flat = blockIdx.y * 8 + blockIdx.x;    // gridDim.x == 8
  int xcd = flat & 7, slot = flat >> 3;      // slot 0..127
  int strip = xcd * 16 + (slot >> 3);        // 128 strips, 16 per XCD
  int nt = slot & 7;
  int bm = strip * 256, bn = nt * 128;

  floatx4 zero4 = {0.f, 0.f, 0.f, 0.f};
  floatx4 acc[4][4];
#pragma unroll
  for (int i = 0; i < 4; i++)
#pragma unroll
    for (int j = 0; j < 4; j++) acc[i][j] = zero4;

  for (int k0 = 0; k0 < K; k0 += 64) {
    __syncthreads();
#pragma unroll
    for (int j = 0; j < 4; j++) {            // A: 256 rows x 64 k (32KB)
      int f = j * 512 + tid;
      int r = f >> 3, c = f & 7;
      int cg = c ^ (r & 7);
      async16(&A[(size_t)(bm + r) * K + k0 + cg * 8], &As[f * 8]);
    }
#pragma unroll
    for (int j = 0; j < 2; j++) {            // B: 128 rows x 64 k (16KB)
      int f = j * 512 + tid;
      int r = f >> 3, c = f & 7;
      int cg = c ^ (r & 7);
      async16(&Bm[(size_t)(bn + r) * K + k0 + cg * 8], &Bs[f * 8]);
    }
    __syncthreads();
#pragma unroll
    for (int kk = 0; kk < 2; kk++) {
      short8 af[4], bfr[4];
      int cgk = kk * 4 + (lane >> 4);
#pragma unroll
      for (int i = 0; i < 4; i++) {
        int m = wm * 64 + i * 16 + (lane & 15);
        af[i] = *(const short8*)&As[m * 64 + ((cgk ^ (m & 7)) * 8)];
        int n = wn * 64 + i * 16 + (lane & 15);
        bfr[i] = *(const short8*)&Bs[n * 64 + ((cgk ^ (n & 7)) * 8)];
      }
#pragma unroll
      for (int i = 0; i < 4; i++)
#pragma unroll
        for (int j = 0; j < 4; j++)
          acc[i][j] = __builtin_amdgcn_mfma_f32_16x16x32_bf16(af[i], bfr[j], acc[i][j], 0, 0, 0);
    }
  }

  // ---- fused transpose epilogue: write vt[h][b][d][t] ----
  int b = bm >> 11, t0 = bm & 2047;
  unsigned short* Ct = smem;                 // 64 cols x (256+8) rows
  const int S = 264;
#pragma unroll 1
  for (int pass = 0; pass < 2; pass++) {
    __syncthreads();
    if (wn == pass) {
#pragma unroll
      for (int i = 0; i < 4; i++) {
#pragma unroll
        for (int j = 0; j < 4; j++) {
          int colL = j * 16 + (lane & 15);
          float bia = bias[bn + pass * 64 + colL];
          int rowb = wm * 64 + i * 16 + (lane >> 4) * 4;
          ushort4 p;
          p.x = f2bf(acc[i][j][0] + bia);
          p.y = f2bf(acc[i][j][1] + bia);
          p.z = f2bf(acc[i][j][2] + bia);
          p.w = f2bf(acc[i][j][3] + bia);
          *(ushort4*)&Ct[colL * S + rowb] = p;
        }
      }
    }
    __syncthreads();
#pragma unroll
    for (int cc = 0; cc < 4; cc++) {
      int colL = wave * 8 + cc * 2 + (lane >> 5);
      int gc = bn + pass * 64 + colL;
      int h = gc >> 6, d = gc & 63;
      int tt = (lane & 31) * 8;
      short8 v = *(const short8*)&Ct[colL * S + tt];
      *(short8*)&vt[((size_t)((h * Bn + b) * HDn + d)) * Tn + t0 + tt] = v;
    }
  }
}

// ================= shared 256x256 BK=64 double-buffered skeleton =================
// 512 threads (8 waves 2x4), 128 KiB LDS. Per K-tile: stage ALL 4 half-tiles of
// tile t+1 (8 loads/thread), ONE counted vmcnt(8) (drains exactly tile t's 8
// loads, never 0), ONE publish barrier, then all 64 MFMAs of tile t in a single
// scheduling window (compiler interleaves ds_reads under MFMAs), ONE closing
// barrier (protects tile t's LDS from tile t+2's stage-writes).
// B fragments for BOTH halves kept in registers (bR[2][2][2]) -> 24 ds_read_b128
// per wave per K-tile (the minimum for a 128x64 wave tile).

#define STAGE_A(kt, half, buf)                                                   \
  {                                                                              \
    _Pragma("unroll")                                                            \
    for (int j_ = 0; j_ < 2; j_++) {                                             \
      int f_ = j_ * 512 + tid;                                                   \
      int r_ = f_ >> 3, c_ = f_ & 7;                                             \
      int cg_ = c_ ^ (r_ & 7);                                                   \
      async16(&Ap[(size_t)(bm + (half) * 128 + r_) * K + (kt) * 64 + cg_ * 8],   \
              &smem[(buf) * 32768 + ((half) * 128 + r_) * 64 + c_ * 8]);         \
    }                                                                            \
  }

#define STAGE_B(kt, half, buf)                                                   \
  {                                                                              \
    _Pragma("unroll")                                                            \
    for (int j_ = 0; j_ < 2; j_++) {                                             \
      int f_ = j_ * 512 + tid;                                                   \
      int r_ = f_ >> 3, c_ = f_ & 7;                                             \
      int cg_ = c_ ^ (r_ & 7);                                                   \
      async16(&Bp[(size_t)(bn + (half) * 128 + r_) * K + (kt) * 64 + cg_ * 8],   \
              &smem[(buf) * 32768 + 16384 + ((half) * 128 + r_) * 64 + c_ * 8]); \
    }                                                                            \
  }

#define LOAD_A(buf, Mh)                                                          \
  {                                                                              \
    _Pragma("unroll")                                                            \
    for (int ii_ = 0; ii_ < 4; ii_++) {                                          \
      int m_ = (Mh) * 128 + wm * 64 + ii_ * 16 + (lane & 15);                    \
      _Pragma("unroll")                                                          \
      for (int kk_ = 0; kk_ < 2; kk_++) {                                        \
        int cgk_ = kk_ * 4 + (lane >> 4);                                        \
        aR[ii_][kk_] =                                                           \
            *(const short8*)&smem[(buf) * 32768 + m_ * 64 + ((cgk_ ^ (m_ & 7)) * 8)]; \
      }                                                                          \
    }                                                                            \
  }

#define LOAD_B(buf, Nh)                                                          \
  {                                                                              \
    _Pragma("unroll")                                                            \
    for (int jj_ = 0; jj_ < 2; jj_++) {                                          \
      int n_ = (Nh) * 128 + wn * 32 + jj_ * 16 + (lane & 15);                    \
      _Pragma("unroll")                                                          \
      for (int kk_ = 0; kk_ < 2; kk_++) {                                        \
        int cgk_ = kk_ * 4 + (lane >> 4);                                        \
        bR[Nh][jj_][kk_] = *(const short8*)&smem[(buf) * 32768 + 16384 + n_ * 64 + \
                                                 ((cgk_ ^ (n_ & 7)) * 8)];       \
      }                                                                          \
    }                                                                            \
  }

#define MFMA16(Mh, Nh)                                                           \
  {                                                                              \
    __builtin_amdgcn_s_setprio(1);                                               \
    _Pragma("unroll")                                                            \
    for (int kk_ = 0; kk_ < 2; kk_++)                                            \
      _Pragma("unroll")                                                          \
      for (int ii_ = 0; ii_ < 4; ii_++)                                          \
        _Pragma("unroll")                                                        \
        for (int jj_ = 0; jj_ < 2; jj_++)                                        \
          acc[(Mh) * 4 + ii_][(Nh) * 2 + jj_] = __builtin_amdgcn_mfma_f32_16x16x32_bf16( \
              aR[ii_][kk_], bR[Nh][jj_][kk_], acc[(Mh) * 4 + ii_][(Nh) * 2 + jj_], 0, 0, 0); \
    __builtin_amdgcn_s_setprio(0);                                               \
  }

#define WAIT8 asm volatile("s_waitcnt vmcnt(8)" ::: "memory")
#define BAR                                                                      \
  {                                                                              \
    asm volatile("" ::: "memory");                                               \
    __builtin_amdgcn_s_barrier();                                                \
    asm volatile("" ::: "memory");                                               \
  }

#define KTILE_BODY(buf, nbuf, tn)                                                \
  {                                                                              \
    STAGE_A(tn, 0, nbuf);                                                        \
    STAGE_B(tn, 0, nbuf);                                                        \
    STAGE_B(tn, 1, nbuf);                                                        \
    STAGE_A(tn, 1, nbuf);                                                        \
    WAIT8; BAR;                                                                  \
    LOAD_A(buf, 0);                                                              \
    LOAD_B(buf, 0);                                                              \
    LOAD_B(buf, 1);                                                              \
    MFMA16(0, 0);                                                                \
    MFMA16(0, 1);                                                                \
    LOAD_A(buf, 1);                                                              \
    MFMA16(1, 1);                                                                \
    MFMA16(1, 0);                                                                \
    BAR;                                                                         \
  }

// ================= GEMM 2: attn @ v (per head) =================
__global__ __launch_bounds__(512, 2)
void k_gemm_attn(const unsigned short* __restrict__ P, const unsigned short* __restrict__ vt,
                 const float* __restrict__ denom, unsigned short* __restrict__ outp) {
  __shared__ unsigned short smem[65536];     // 128 KiB: 2 x (A 256x64 | B 256x64)
  const int K = Tn;
  int tid = threadIdx.x;
  int wave = tid >> 6, lane = tid & 63;
  int wm = wave >> 2, wn = wave & 3;         // per-quadrant: 2x4 waves of 64x32

  int flat = blockIdx.y * 8 + blockIdx.x;    // gridDim = (8, 64)
  int wg = (flat & 7) * 64 + (flat >> 3);    // 64 consecutive tiles per XCD (2 heads)
  int h = wg >> 5;                           // 32 tiles per head (8 M x 4 N)
  int mt = (wg >> 2) & 7, nt = wg & 3;
  int bm = mt * 256, bn = nt * 256;

  const unsigned short* Ap = P + (size_t)h * Tn * Tn;
  const unsigned short* Bp = vt + (size_t)h * (Bn * HDn) * Tn;

  floatx4 zero4 = {0.f, 0.f, 0.f, 0.f};
  floatx4 acc[8][4];
#pragma unroll
  for (int i = 0; i < 8; i++)
#pragma unroll
    for (int j = 0; j < 4; j++) acc[i][j] = zero4;

  short8 aR[4][2], bR[2][2][2];

  // prologue: stage K-tile 0 into buf0 (same order as steady state)
  STAGE_A(0, 0, 0);
  STAGE_B(0, 0, 0);
  STAGE_B(0, 1, 0);
  STAGE_A(0, 1, 0);

  const int nk = K / 64;                     // 32
  for (int t = 0; t < nk; t++) {
    int buf = t & 1, nbuf = buf ^ 1;
    int tn = (t < nk - 1) ? t + 1 : nk - 1;  // clamp: last iter restages (harmless)
    KTILE_BODY(buf, nbuf, tn);
  }
  asm volatile("s_waitcnt vmcnt(0)" ::: "memory");  // drain before endpgm

  // epilogue: scale by 1/denom, scatter col=(b,d) -> outp[b][row][h*64+d]
#pragma unroll
  for (int i = 0; i < 8; i++) {
    int rb = bm + (i >> 2) * 128 + wm * 64 + (i & 3) * 16 + (lane >> 4) * 4;
#pragma unroll
    for (int r = 0; r < 4; r++) {
      int row = rb + r;
      float sc = 1.f / denom[(size_t)h * Tn + row];
#pragma unroll
      for (int j = 0; j < 4; j++) {
        int col = bn + (j >> 1) * 128 + wn * 32 + (j & 1) * 16 + (lane & 15);
        int b = col >> 6, d = col & 63;
        outp[((size_t)(b * Tn + row)) * En + h * HDn + d] = f2bf(acc[i][j][r] * sc);
      }
    }
  }
}

// ================= GEMM 3: out = o@Wo^T + bo, 256x256 block (same skeleton) =================
__global__ __launch_bounds__(512, 2)
void k_gemm_out(const unsigned short* __restrict__ A, const unsigned short* __restrict__ Bm,
                const float* __restrict__ bias, float* __restrict__ out) {
  __shared__ unsigned short smem[65536];     // 128 KiB
  const int K = 1024, N = 1024;
  int tid = threadIdx.x;
  int wave = tid >> 6, lane = tid & 63;
  int wm = wave >> 2, wn = wave & 3;

  int flat = blockIdx.y * 8 + blockIdx.x;    // gridDim = (8, 64)
  int wg = (flat & 7) * 64 + (flat >> 3);    // 512 blocks: 128 mt x 4 nt
  int mt = wg >> 2, nt = wg & 3;
  int bm = mt * 256, bn = nt * 256;

  const unsigned short* Ap = A;
  const unsigned short* Bp = Bm;

  floatx4 zero4 = {0.f, 0.f, 0.f, 0.f};
  floatx4 acc[8][4];
#pragma unroll
  for (int i = 0; i < 8; i++)
#pragma unroll
    for (int j = 0; j < 4; j++) acc[i][j] = zero4;

  short8 aR[4][2], bR[2][2][2];

  STAGE_A(0, 0, 0);
  STAGE_B(0, 0, 0);
  STAGE_B(0, 1, 0);
  STAGE_A(0, 1, 0);

  const int nk = K / 64;                     // 16
  for (int t = 0; t < nk; t++) {
    int buf = t & 1, nbuf = buf ^ 1;
    int tn = (t < nk - 1) ? t + 1 : nk - 1;
    KTILE_BODY(buf, nbuf, tn);
  }
  asm volatile("s_waitcnt vmcnt(0)" ::: "memory");

#pragma unroll
  for (int i = 0; i < 8; i++) {
    int rb = bm + (i >> 2) * 128 + wm * 64 + (i & 3) * 16 + (lane >> 4) * 4;
#pragma unroll
    for (int r = 0; r < 4; r++) {
      int row = rb + r;
#pragma unroll
      for (int j = 0; j < 4; j++) {
        int col = bn + (j >> 1) * 128 + wn * 32 + (j & 1) * 16 + (lane & 15);
        out[(size_t)row * N + col] = acc[i][j][r] + bias[col];
      }
    }
  }
}

extern "C" void kernel_launch(void* const* d_in, const int* in_sizes, int n_in,
                              void* d_out, int out_size, void* d_ws, size_t ws_size,
                              hipStream_t stream) {
  const float* x      = (const float*)d_in[0];
  // d_in[1..4] = Wq, bq, Wk, bk — unused by the reference
  const float* Wv     = (const float*)d_in[5];
  const float* bv     = (const float*)d_in[6];
  const float* A_log  = (const float*)d_in[7];
  const float* A_bias = (const float*)d_in[8];
  const float* L      = (const float*)d_in[9];
  const float* Lb     = (const float*)d_in[10];
  const float* Wo     = (const float*)d_in[11];
  const float* bo     = (const float*)d_in[12];
  const int* levels   = (const int*)d_in[13];
  float* out = (float*)d_out;

  // workspace layout (bytes); Pw aliases xb (dead after k_gemm_v)
  char* ws = (char*)d_ws;
  float* cs            = (float*)(ws + 0);                  // 128 KiB
  float* denom         = (float*)(ws + 131072);             // 128 KiB
  unsigned short* Wvb  = (unsigned short*)(ws + 262144);    // 2 MiB
  unsigned short* Wob  = (unsigned short*)(ws + 2359296);   // 2 MiB
  unsigned short* xb   = (unsigned short*)(ws + 4456448);   // 64 MiB
  unsigned short* Pw   = (unsigned short*)(ws + 4456448);   // 128 MiB (aliases xb)
  unsigned short* vt   = (unsigned short*)(ws + 138674176); // 64 MiB
  unsigned short* outp = (unsigned short*)(ws + 205783040); // 64 MiB
  if (ws_size < 272891904ULL) return;

  int nx4 = Bn * Tn * En / 4;
  k_cvt<<<(nx4 + 255) / 256, 256, 0, stream>>>(x, xb, nx4);
  int nw4 = En * En / 4;
  k_cvt<<<(nw4 + 255) / 256, 256, 0, stream>>>(Wv, Wvb, nw4);
  k_cvt<<<(nw4 + 255) / 256, 256, 0, stream>>>(Wo, Wob, nw4);
  k_scan<<<NHn, 256, 0, stream>>>(A_log, A_bias, cs);

  k_gemm_v<<<dim3(8, 128), 512, 0, stream>>>(xb, Wvb, bv, vt);

  k_weights<<<Tn, 256, 0, stream>>>(L, Lb, levels, cs, Pw, denom);

  k_gemm_attn<<<dim3(8, 64), 512, 0, stream>>>(Pw, vt, denom, outp);

  k_gemm_out<<<dim3(8, 64), 512, 0, stream>>>(outp, Wob, bo, out);
}

// Round 4
// 604.733 us; speedup vs baseline: 1.1036x; 1.0229x over previous
//
#include <hip/hip_runtime.h>
#include <stdint.h>

static constexpr int Bn = 16, Tn = 2048, En = 1024, NHn = 16, HDn = 64, NLEVn = 12;

typedef __attribute__((ext_vector_type(8))) short short8;
typedef __attribute__((ext_vector_type(4))) float floatx4;

__device__ __forceinline__ unsigned short f2bf(float f) {
  unsigned int u = __float_as_uint(f);
  u += 0x7fffu + ((u >> 16) & 1u);
  return (unsigned short)(u >> 16);
}
__device__ __forceinline__ float bf2f(unsigned short s) {
  return __uint_as_float(((unsigned int)s) << 16);
}

__device__ __forceinline__ void async16(const unsigned short* g, unsigned short* l) {
  __builtin_amdgcn_global_load_lds(
      (const __attribute__((address_space(1))) unsigned int*)g,
      (__attribute__((address_space(3))) unsigned int*)l, 16, 0, 0);
}

// ---------------- fp32 -> bf16 convert ----------------
__global__ void k_cvt(const float* __restrict__ in, unsigned short* __restrict__ out, int n4) {
  int i = blockIdx.x * 256 + threadIdx.x;
  if (i < n4) {
    float4 v = ((const float4*)in)[i];
    ushort4 o;
    o.x = f2bf(v.x); o.y = f2bf(v.y); o.z = f2bf(v.z); o.w = f2bf(v.w);
    ((ushort4*)out)[i] = o;
  }
}

// ---------------- per-head prefix scan of log(sigmoid(A)) ----------------
__global__ void k_scan(const float* __restrict__ A_log, const float* __restrict__ A_bias,
                       float* __restrict__ cs) {
  int h = blockIdx.x;
  int tid = threadIdx.x;
  __shared__ float part[256];
  float loc[8];
  float run = 0.f;
#pragma unroll
  for (int j = 0; j < 8; j++) {
    int t = tid * 8 + j;
    float x = A_log[t * NHn + h] + A_bias[t * NHn + h];
    float ls = -log1pf(__expf(-x));
    run += ls;
    loc[j] = run;
  }
  part[tid] = run;
  __syncthreads();
  for (int d = 1; d < 256; d <<= 1) {
    float v = (tid >= d) ? part[tid - d] : 0.f;
    __syncthreads();
    part[tid] += v;
    __syncthreads();
  }
  float off = (tid > 0) ? part[tid - 1] : 0.f;
#pragma unroll
  for (int j = 0; j < 8; j++) cs[(tid * 8 + j) * NHn + h] = loc[j] + off;
}

// ---------------- unnormalized weights P[h][t][s] (bf16) + row sums ----------------
__global__ void k_weights(const float* __restrict__ L, const float* __restrict__ Lb,
                          const int* __restrict__ levels, const float* __restrict__ cs,
                          unsigned short* __restrict__ P, float* __restrict__ denom) {
  int t = blockIdx.x;
  int tid = threadIdx.x;
  __shared__ float Lrow[NHn * NLEVn];
  __shared__ float cst[NHn];
  __shared__ float dsum[NHn];
  if (tid < NHn * NLEVn) Lrow[tid] = L[t * NHn * NLEVn + tid] + Lb[t * NHn * NLEVn + tid];
  if (tid < NHn) { cst[tid] = cs[t * NHn + tid]; dsum[tid] = 0.f; }
  __syncthreads();
  float acc[NHn];
#pragma unroll
  for (int h = 0; h < NHn; h++) acc[h] = 0.f;
  for (int s = tid; s < Tn; s += 256) {
    int lev = levels[(size_t)t * Tn + s];
    bool causal = (s <= t);
    float csr[NHn];
    const float4* c4 = (const float4*)(cs + s * NHn);
#pragma unroll
    for (int q = 0; q < 4; q++) {
      float4 v = c4[q];
      csr[q * 4 + 0] = v.x; csr[q * 4 + 1] = v.y; csr[q * 4 + 2] = v.z; csr[q * 4 + 3] = v.w;
    }
#pragma unroll
    for (int h = 0; h < NHn; h++) {
      float w = 1.f;   // exp(0) for s > t (mask writes 0, not -inf)
      if (causal) {
        float dec = __expf(cst[h] - csr[h]);
        w = __expf(Lrow[h * NLEVn + lev] * dec);
      }
      unsigned short pb = f2bf(w);
      acc[h] += bf2f(pb);
      P[((size_t)h * Tn + t) * Tn + s] = pb;
    }
  }
  int lane = tid & 63;
#pragma unroll
  for (int h = 0; h < NHn; h++) {
    float v = acc[h];
    for (int o = 32; o > 0; o >>= 1) v += __shfl_down(v, o, 64);
    if (lane == 0) atomicAdd(&dsum[h], v);
  }
  __syncthreads();
  if (tid < NHn) denom[(size_t)tid * Tn + t] = dsum[tid];
}

// ================= GEMM 1: v = x@Wv^T + bv, 256x128 block, fused transpose =================
__global__ __launch_bounds__(512)
void k_gemm_v(const unsigned short* __restrict__ A, const unsigned short* __restrict__ Bm,
              const float* __restrict__ bias, unsigned short* __restrict__ vt) {
  __shared__ unsigned short smem[24576];     // 48 KB: As(32K) | Bs(16K); epilogue reuses as Ct
  unsigned short* As = smem;                 // 256 x 64
  unsigned short* Bs = smem + 16384;         // 128 x 64
  const int K = 1024;
  int tid = threadIdx.x;
  int wave = tid >> 6, lane = tid & 63;
  int wm = wave >> 1, wn = wave & 1;         // 4 x 2 waves of 64x64 tiles

  int flat = blockIdx.y * 8 + blockIdx.x;    // gridDim.x == 8
  int xcd = flat & 7, slot = flat >> 3;      // slot 0..127
  int strip = xcd * 16 + (slot >> 3);        // 128 strips, 16 per XCD
  int nt = slot & 7;
  int bm = strip * 256, bn = nt * 128;

  floatx4 zero4 = {0.f, 0.f, 0.f, 0.f};
  floatx4 acc[4][4];
#pragma unroll
  for (int i = 0; i < 4; i++)
#pragma unroll
    for (int j = 0; j < 4; j++) acc[i][j] = zero4;

  for (int k0 = 0; k0 < K; k0 += 64) {
    __syncthreads();
#pragma unroll
    for (int j = 0; j < 4; j++) {            // A: 256 rows x 64 k (32KB)
      int f = j * 512 + tid;
      int r = f >> 3, c = f & 7;
      int cg = c ^ (r & 7);
      async16(&A[(size_t)(bm + r) * K + k0 + cg * 8], &As[f * 8]);
    }
#pragma unroll
    for (int j = 0; j < 2; j++) {            // B: 128 rows x 64 k (16KB)
      int f = j * 512 + tid;
      int r = f >> 3, c = f & 7;
      int cg = c ^ (r & 7);
      async16(&Bm[(size_t)(bn + r) * K + k0 + cg * 8], &Bs[f * 8]);
    }
    __syncthreads();
#pragma unroll
    for (int kk = 0; kk < 2; kk++) {
      short8 af[4], bfr[4];
      int cgk = kk * 4 + (lane >> 4);
#pragma unroll
      for (int i = 0; i < 4; i++) {
        int m = wm * 64 + i * 16 + (lane & 15);
        af[i] = *(const short8*)&As[m * 64 + ((cgk ^ (m & 7)) * 8)];
        int n = wn * 64 + i * 16 + (lane & 15);
        bfr[i] = *(const short8*)&Bs[n * 64 + ((cgk ^ (n & 7)) * 8)];
      }
#pragma unroll
      for (int i = 0; i < 4; i++)
#pragma unroll
        for (int j = 0; j < 4; j++)
          acc[i][j] = __builtin_amdgcn_mfma_f32_16x16x32_bf16(af[i], bfr[j], acc[i][j], 0, 0, 0);
    }
  }

  // ---- fused transpose epilogue: write vt[h][b][d][t] ----
  int b = bm >> 11, t0 = bm & 2047;
  unsigned short* Ct = smem;                 // 64 cols x (256+8) rows
  const int S = 264;
#pragma unroll 1
  for (int pass = 0; pass < 2; pass++) {
    __syncthreads();
    if (wn == pass) {
#pragma unroll
      for (int i = 0; i < 4; i++) {
#pragma unroll
        for (int j = 0; j < 4; j++) {
          int colL = j * 16 + (lane & 15);
          float bia = bias[bn + pass * 64 + colL];
          int rowb = wm * 64 + i * 16 + (lane >> 4) * 4;
          ushort4 p;
          p.x = f2bf(acc[i][j][0] + bia);
          p.y = f2bf(acc[i][j][1] + bia);
          p.z = f2bf(acc[i][j][2] + bia);
          p.w = f2bf(acc[i][j][3] + bia);
          *(ushort4*)&Ct[colL * S + rowb] = p;
        }
      }
    }
    __syncthreads();
#pragma unroll
    for (int cc = 0; cc < 4; cc++) {
      int colL = wave * 8 + cc * 2 + (lane >> 5);
      int gc = bn + pass * 64 + colL;
      int h = gc >> 6, d = gc & 63;
      int tt = (lane & 31) * 8;
      short8 v = *(const short8*)&Ct[colL * S + tt];
      *(short8*)&vt[((size_t)((h * Bn + b) * HDn + d)) * Tn + t0 + tt] = v;
    }
  }
}

// ================= shared 256x256 BK=64 double-buffered skeleton =================
// 512 threads (8 waves 2x4), 128 KiB LDS. m201-style phase ordering: each phase
// issues its ds_reads FIRST (they fly across the barrier-convergence window),
// then one stage group (2 global_load_lds), then counted vmcnt(4) + barrier,
// then the 16-MFMA cluster (operands already in flight / landed), then barrier.
// vmcnt(4) keeps the 2 newest stage-groups in flight (never drains to 0).
// Publish schedule (stage order Ah0,Bh0,Bh1,Ah1 of tile t+1 across phases):
//   after P1-bar: Ah0,Bh0,Bh1[t] readable; after P2-bar: +Ah1[t];
//   after P4-bar: Ah0,Bh0[t+1] readable -> P1 of iter t+1 may read them at top.
// Fragment liveness peaks at 48 VGPR (aR one half + bR one half + overlap).

#define STAGE_A(kt, half, buf)                                                   \
  {                                                                              \
    _Pragma("unroll")                                                            \
    for (int j_ = 0; j_ < 2; j_++) {                                             \
      int f_ = j_ * 512 + tid;                                                   \
      int r_ = f_ >> 3, c_ = f_ & 7;                                             \
      int cg_ = c_ ^ (r_ & 7);                                                   \
      async16(&Ap[(size_t)(bm + (half) * 128 + r_) * K + (kt) * 64 + cg_ * 8],   \
              &smem[(buf) * 32768 + ((half) * 128 + r_) * 64 + c_ * 8]);         \
    }                                                                            \
  }

#define STAGE_B(kt, half, buf)                                                   \
  {                                                                              \
    _Pragma("unroll")                                                            \
    for (int j_ = 0; j_ < 2; j_++) {                                             \
      int f_ = j_ * 512 + tid;                                                   \
      int r_ = f_ >> 3, c_ = f_ & 7;                                             \
      int cg_ = c_ ^ (r_ & 7);                                                   \
      async16(&Bp[(size_t)(bn + (half) * 128 + r_) * K + (kt) * 64 + cg_ * 8],   \
              &smem[(buf) * 32768 + 16384 + ((half) * 128 + r_) * 64 + c_ * 8]); \
    }                                                                            \
  }

#define LOAD_A(buf, Mh)                                                          \
  {                                                                              \
    _Pragma("unroll")                                                            \
    for (int ii_ = 0; ii_ < 4; ii_++) {                                          \
      int m_ = (Mh) * 128 + wm * 64 + ii_ * 16 + (lane & 15);                    \
      _Pragma("unroll")                                                          \
      for (int kk_ = 0; kk_ < 2; kk_++) {                                        \
        int cgk_ = kk_ * 4 + (lane >> 4);                                        \
        aR[ii_][kk_] =                                                           \
            *(const short8*)&smem[(buf) * 32768 + m_ * 64 + ((cgk_ ^ (m_ & 7)) * 8)]; \
      }                                                                          \
    }                                                                            \
  }

#define LOAD_B(buf, Nh)                                                          \
  {                                                                              \
    _Pragma("unroll")                                                            \
    for (int jj_ = 0; jj_ < 2; jj_++) {                                          \
      int n_ = (Nh) * 128 + wn * 32 + jj_ * 16 + (lane & 15);                    \
      _Pragma("unroll")                                                          \
      for (int kk_ = 0; kk_ < 2; kk_++) {                                        \
        int cgk_ = kk_ * 4 + (lane >> 4);                                        \
        bR[jj_][kk_] = *(const short8*)&smem[(buf) * 32768 + 16384 + n_ * 64 +   \
                                             ((cgk_ ^ (n_ & 7)) * 8)];           \
      }                                                                          \
    }                                                                            \
  }

#define MFMA16(Mh, Nh)                                                           \
  {                                                                              \
    __builtin_amdgcn_s_setprio(1);                                               \
    _Pragma("unroll")                                                            \
    for (int kk_ = 0; kk_ < 2; kk_++)                                            \
      _Pragma("unroll")                                                          \
      for (int ii_ = 0; ii_ < 4; ii_++)                                          \
        _Pragma("unroll")                                                        \
        for (int jj_ = 0; jj_ < 2; jj_++)                                        \
          acc[(Mh) * 4 + ii_][(Nh) * 2 + jj_] = __builtin_amdgcn_mfma_f32_16x16x32_bf16( \
              aR[ii_][kk_], bR[jj_][kk_], acc[(Mh) * 4 + ii_][(Nh) * 2 + jj_], 0, 0, 0); \
    __builtin_amdgcn_s_setprio(0);                                               \
  }

#define WAIT4 asm volatile("s_waitcnt vmcnt(4)" ::: "memory")
#define LGKM8 asm volatile("s_waitcnt lgkmcnt(8)" ::: "memory")
#define BAR                                                                      \
  {                                                                              \
    asm volatile("" ::: "memory");                                               \
    __builtin_amdgcn_s_barrier();                                                \
    asm volatile("" ::: "memory");                                               \
  }

#define KTILE_BODY(buf, nbuf, tn)                                                \
  {                                                                              \
    /* P1: reads for (0,0); stage Ah0[t+1] */                                    \
    LOAD_A(buf, 0);                                                              \
    LOAD_B(buf, 0);                                                              \
    STAGE_A(tn, 0, nbuf);                                                        \
    LGKM8;                                                                       \
    WAIT4; BAR;                                                                  \
    MFMA16(0, 0);                                                                \
    BAR;                                                                         \
    /* P2: reads for (0,1); stage Bh0[t+1] */                                    \
    LOAD_B(buf, 1);                                                              \
    STAGE_B(tn, 0, nbuf);                                                        \
    WAIT4; BAR;                                                                  \
    MFMA16(0, 1);                                                                \
    BAR;                                                                         \
    /* P3: reads for (1,1); stage Bh1[t+1] */                                    \
    LOAD_A(buf, 1);                                                              \
    STAGE_B(tn, 1, nbuf);                                                        \
    WAIT4; BAR;                                                                  \
    MFMA16(1, 1);                                                                \
    BAR;                                                                         \
    /* P4: reads for (1,0) (B0 re-read); stage Ah1[t+1] */                       \
    LOAD_B(buf, 0);                                                              \
    STAGE_A(tn, 1, nbuf);                                                        \
    WAIT4; BAR;                                                                  \
    MFMA16(1, 0);                                                                \
    BAR;                                                                         \
  }

// ================= GEMM 2: attn @ v (per head) =================
__global__ __launch_bounds__(512, 2)
void k_gemm_attn(const unsigned short* __restrict__ P, const unsigned short* __restrict__ vt,
                 const float* __restrict__ denom, unsigned short* __restrict__ outp) {
  __shared__ unsigned short smem[65536];     // 128 KiB: 2 x (A 256x64 | B 256x64)
  const int K = Tn;
  int tid = threadIdx.x;
  int wave = tid >> 6, lane = tid & 63;
  int wm = wave >> 2, wn = wave & 3;         // per-quadrant: 2x4 waves of 64x32

  int flat = blockIdx.y * 8 + blockIdx.x;    // gridDim = (8, 64)
  int wg = (flat & 7) * 64 + (flat >> 3);    // 64 consecutive tiles per XCD (2 heads)
  int h = wg >> 5;                           // 32 tiles per head (8 M x 4 N)
  int mt = (wg >> 2) & 7, nt = wg & 3;
  int bm = mt * 256, bn = nt * 256;

  const unsigned short* Ap = P + (size_t)h * Tn * Tn;
  const unsigned short* Bp = vt + (size_t)h * (Bn * HDn) * Tn;

  floatx4 zero4 = {0.f, 0.f, 0.f, 0.f};
  floatx4 acc[8][4];
#pragma unroll
  for (int i = 0; i < 8; i++)
#pragma unroll
    for (int j = 0; j < 4; j++) acc[i][j] = zero4;

  short8 aR[4][2], bR[2][2];

  // prologue: stage K-tile 0 into buf0, publish Ah0,Bh0 (keep Bh1,Ah1 in flight)
  STAGE_A(0, 0, 0);
  STAGE_B(0, 0, 0);
  STAGE_B(0, 1, 0);
  STAGE_A(0, 1, 0);
  WAIT4; BAR;

  const int nk = K / 64;                     // 32
  for (int t = 0; t < nk; t++) {
    int buf = t & 1, nbuf = buf ^ 1;
    int tn = (t < nk - 1) ? t + 1 : nk - 1;  // clamp: last iter restages (harmless)
    KTILE_BODY(buf, nbuf, tn);
  }
  asm volatile("s_waitcnt vmcnt(0)" ::: "memory");  // drain before endpgm

  // epilogue: scale by 1/denom, scatter col=(b,d) -> outp[b][row][h*64+d]
#pragma unroll
  for (int i = 0; i < 8; i++) {
    int rb = bm + (i >> 2) * 128 + wm * 64 + (i & 3) * 16 + (lane >> 4) * 4;
#pragma unroll
    for (int r = 0; r < 4; r++) {
      int row = rb + r;
      float sc = 1.f / denom[(size_t)h * Tn + row];
#pragma unroll
      for (int j = 0; j < 4; j++) {
        int col = bn + (j >> 1) * 128 + wn * 32 + (j & 1) * 16 + (lane & 15);
        int b = col >> 6, d = col & 63;
        outp[((size_t)(b * Tn + row)) * En + h * HDn + d] = f2bf(acc[i][j][r] * sc);
      }
    }
  }
}

// ================= GEMM 3: out = o@Wo^T + bo, 256x256 block (same skeleton) =================
__global__ __launch_bounds__(512, 2)
void k_gemm_out(const unsigned short* __restrict__ A, const unsigned short* __restrict__ Bm,
                const float* __restrict__ bias, float* __restrict__ out) {
  __shared__ unsigned short smem[65536];     // 128 KiB
  const int K = 1024, N = 1024;
  int tid = threadIdx.x;
  int wave = tid >> 6, lane = tid & 63;
  int wm = wave >> 2, wn = wave & 3;

  int flat = blockIdx.y * 8 + blockIdx.x;    // gridDim = (8, 64)
  int wg = (flat & 7) * 64 + (flat >> 3);    // 512 blocks: 128 mt x 4 nt
  int mt = wg >> 2, nt = wg & 3;
  int bm = mt * 256, bn = nt * 256;

  const unsigned short* Ap = A;
  const unsigned short* Bp = Bm;

  floatx4 zero4 = {0.f, 0.f, 0.f, 0.f};
  floatx4 acc[8][4];
#pragma unroll
  for (int i = 0; i < 8; i++)
#pragma unroll
    for (int j = 0; j < 4; j++) acc[i][j] = zero4;

  short8 aR[4][2], bR[2][2];

  STAGE_A(0, 0, 0);
  STAGE_B(0, 0, 0);
  STAGE_B(0, 1, 0);
  STAGE_A(0, 1, 0);
  WAIT4; BAR;

  const int nk = K / 64;                     // 16
  for (int t = 0; t < nk; t++) {
    int buf = t & 1, nbuf = buf ^ 1;
    int tn = (t < nk - 1) ? t + 1 : nk - 1;
    KTILE_BODY(buf, nbuf, tn);
  }
  asm volatile("s_waitcnt vmcnt(0)" ::: "memory");

#pragma unroll
  for (int i = 0; i < 8; i++) {
    int rb = bm + (i >> 2) * 128 + wm * 64 + (i & 3) * 16 + (lane >> 4) * 4;
#pragma unroll
    for (int r = 0; r < 4; r++) {
      int row = rb + r;
#pragma unroll
      for (int j = 0; j < 4; j++) {
        int col = bn + (j >> 1) * 128 + wn * 32 + (j & 1) * 16 + (lane & 15);
        out[(size_t)row * N + col] = acc[i][j][r] + bias[col];
      }
    }
  }
}

extern "C" void kernel_launch(void* const* d_in, const int* in_sizes, int n_in,
                              void* d_out, int out_size, void* d_ws, size_t ws_size,
                              hipStream_t stream) {
  const float* x      = (const float*)d_in[0];
  // d_in[1..4] = Wq, bq, Wk, bk — unused by the reference
  const float* Wv     = (const float*)d_in[5];
  const float* bv     = (const float*)d_in[6];
  const float* A_log  = (const float*)d_in[7];
  const float* A_bias = (const float*)d_in[8];
  const float* L      = (const float*)d_in[9];
  const float* Lb     = (const float*)d_in[10];
  const float* Wo     = (const float*)d_in[11];
  const float* bo     = (const float*)d_in[12];
  const int* levels   = (const int*)d_in[13];
  float* out = (float*)d_out;

  // workspace layout (bytes); Pw aliases xb (dead after k_gemm_v)
  char* ws = (char*)d_ws;
  float* cs            = (float*)(ws + 0);                  // 128 KiB
  float* denom         = (float*)(ws + 131072);             // 128 KiB
  unsigned short* Wvb  = (unsigned short*)(ws + 262144);    // 2 MiB
  unsigned short* Wob  = (unsigned short*)(ws + 2359296);   // 2 MiB
  unsigned short* xb   = (unsigned short*)(ws + 4456448);   // 64 MiB
  unsigned short* Pw   = (unsigned short*)(ws + 4456448);   // 128 MiB (aliases xb)
  unsigned short* vt   = (unsigned short*)(ws + 138674176); // 64 MiB
  unsigned short* outp = (unsigned short*)(ws + 205783040); // 64 MiB
  if (ws_size < 272891904ULL) return;

  int nx4 = Bn * Tn * En / 4;
  k_cvt<<<(nx4 + 255) / 256, 256, 0, stream>>>(x, xb, nx4);
  int nw4 = En * En / 4;
  k_cvt<<<(nw4 + 255) / 256, 256, 0, stream>>>(Wv, Wvb, nw4);
  k_cvt<<<(nw4 + 255) / 256, 256, 0, stream>>>(Wo, Wob, nw4);
  k_scan<<<NHn, 256, 0, stream>>>(A_log, A_bias, cs);

  k_gemm_v<<<dim3(8, 128), 512, 0, stream>>>(xb, Wvb, bv, vt);

  k_weights<<<Tn, 256, 0, stream>>>(L, Lb, levels, cs, Pw, denom);

  k_gemm_attn<<<dim3(8, 64), 512, 0, stream>>>(Pw, vt, denom, outp);

  k_gemm_out<<<dim3(8, 64), 512, 0, stream>>>(outp, Wob, bo, out);
}